// Round 1
// baseline (17850.571 us; speedup 1.0000x reference)
//
#include <hip/hip_runtime.h>
#include <hip/hip_bf16.h>

// Problem constants (fixed by the reference):
// x: (B=4, T=5, C=3, H=128, W=128) fp32 ; R=2 ; D = T*C*R*R = 60
// xf: (B, D, N) with N = 64*64 = 4096
#define BB 4
#define TC 15        // T*C
#define DD 60
#define NN 4096
#define HH 128
#define CHUNKS (NN / 256)   // 16

// ---------------- Kernel 1: pixel-unshuffle gather  x -> xf (B, D, N) ----------------
__global__ __launch_bounds__(256) void k_unshuffle(const float* __restrict__ x,
                                                   float* __restrict__ xf) {
    int idx = blockIdx.x * 256 + threadIdx.x;          // over B*D*N = 983040
    if (idx >= BB * DD * NN) return;
    int n = idx & (NN - 1);
    int d = (idx >> 12) % DD;
    int b = idx / (DD * NN);
    int oh = n >> 6, ow = n & 63;
    int c1 = d >> 2, r1 = (d >> 1) & 1, r2 = d & 1;
    // x flat index: ((b*TC + c1)*H + (oh*2+r1))*W + (ow*2+r2)
    xf[idx] = x[((b * TC + c1) * HH + oh * 2 + r1) * HH + ow * 2 + r2];
}

// ---------------- Kernel 2: G[b,o,n] = g_b[o] + sum_d g_w[o,d]*xf[b,d,n] ----------------
__global__ __launch_bounds__(256) void k_gproj(const float* __restrict__ xf,
                                               const float* __restrict__ g_w,
                                               const float* __restrict__ g_b,
                                               float* __restrict__ G) {
    int idx = blockIdx.x * 256 + threadIdx.x;          // over B*D*N, n fastest
    if (idx >= BB * DD * NN) return;
    int n = idx & (NN - 1);
    int o = (idx >> 12) % DD;
    int b = idx / (DD * NN);
    const float* K = xf + b * DD * NN;
    float acc = g_b[o];
    #pragma unroll
    for (int d = 0; d < DD; ++d)
        acc += g_w[o * DD + d] * K[d * NN + n];
    G[idx] = acc;
}

// ---------------- Kernel 3: attention. One block per (b, n) query row. ----------------
// Y[b,n,o] = sum_m softmax_m(q . k_m) * G[b,o,m]
__global__ __launch_bounds__(256) void k_attn(const float* __restrict__ xf,
                                              const float* __restrict__ G,
                                              float* __restrict__ Y) {
    int bn = blockIdx.x;            // b*N + n
    int b  = bn >> 12;
    int n  = bn & (NN - 1);
    const float* K  = xf + b * DD * NN;
    const float* Gb = G  + b * DD * NN;
    int tid  = threadIdx.x;
    int lane = tid & 63;
    int wave = tid >> 6;

    __shared__ float q[DD];
    if (tid < DD) q[tid] = K[tid * NN + n];
    __syncthreads();

    // Pass 1: scores for this thread's 16 key columns (m = i*256 + tid)
    float s[CHUNKS];
    float mmax = -1e30f;
    #pragma unroll
    for (int i = 0; i < CHUNKS; ++i) {
        int m = i * 256 + tid;
        float acc = 0.f;
        #pragma unroll
        for (int d = 0; d < DD; ++d) acc += q[d] * K[d * NN + m];
        s[i] = acc;
        mmax = fmaxf(mmax, acc);
    }

    // Pass 2: per-thread exp + weighted accumulation of V rows
    float acc[DD];
    #pragma unroll
    for (int o = 0; o < DD; ++o) acc[o] = 0.f;
    float l = 0.f;
    #pragma unroll
    for (int i = 0; i < CHUNKS; ++i) {
        int m = i * 256 + tid;
        float w = __expf(s[i] - mmax);
        l += w;
        #pragma unroll
        for (int o = 0; o < DD; ++o) acc[o] += w * Gb[o * NN + m];
    }

    // ---- merge 256 partials (each has own mmax, l, acc[60]) ----
    __shared__ float smax[4];
    __shared__ float ssum[4];
    __shared__ float part[4][DD];

    float wm = mmax;
    #pragma unroll
    for (int off = 1; off < 64; off <<= 1) wm = fmaxf(wm, __shfl_xor(wm, off));
    if (lane == 0) smax[wave] = wm;
    __syncthreads();
    float M = fmaxf(fmaxf(smax[0], smax[1]), fmaxf(smax[2], smax[3]));

    float f = __expf(mmax - M);
    float lf = l * f;
    #pragma unroll
    for (int off = 1; off < 64; off <<= 1) lf += __shfl_xor(lf, off);
    if (lane == 0) ssum[wave] = lf;

    #pragma unroll
    for (int o = 0; o < DD; ++o) {
        float v = acc[o] * f;
        #pragma unroll
        for (int off = 1; off < 64; off <<= 1) v += __shfl_xor(v, off);
        if (lane == 0) part[wave][o] = v;
    }
    __syncthreads();

    if (tid < DD) {
        float L = ssum[0] + ssum[1] + ssum[2] + ssum[3];
        float y = part[0][tid] + part[1][tid] + part[2][tid] + part[3][tid];
        Y[bn * DD + tid] = y / L;   // Y stored as (B, N, D)
    }
}

// ---------------- Kernel 4: out = pixel_shuffle(w_w . Y + w_b) + x ----------------
__global__ __launch_bounds__(256) void k_out(const float* __restrict__ Y,
                                             const float* __restrict__ w_w,
                                             const float* __restrict__ w_b,
                                             const float* __restrict__ x,
                                             float* __restrict__ out) {
    int idx = blockIdx.x * 256 + threadIdx.x;          // over B*D*N, n fastest
    if (idx >= BB * DD * NN) return;
    int n = idx & (NN - 1);
    int o = (idx >> 12) % DD;
    int b = idx / (DD * NN);
    const float* Yb = Y + b * NN * DD;
    float acc = w_b[o];
    #pragma unroll
    for (int d = 0; d < DD; ++d)
        acc += w_w[o * DD + d] * Yb[n * DD + d];
    int oh = n >> 6, ow = n & 63;
    int c1 = o >> 2, r1 = (o >> 1) & 1, r2 = o & 1;
    int xi = ((b * TC + c1) * HH + oh * 2 + r1) * HH + ow * 2 + r2;
    out[xi] = acc + x[xi];
}

extern "C" void kernel_launch(void* const* d_in, const int* in_sizes, int n_in,
                              void* d_out, int out_size, void* d_ws, size_t ws_size,
                              hipStream_t stream) {
    const float* x   = (const float*)d_in[0];
    const float* g_w = (const float*)d_in[1];
    const float* g_b = (const float*)d_in[2];
    const float* w_w = (const float*)d_in[3];
    const float* w_b = (const float*)d_in[4];
    float* out = (float*)d_out;

    const int elems = BB * DD * NN;                    // 983040
    float* xf = (float*)d_ws;                          // (B, D, N)
    float* G  = xf + elems;                            // (B, D, N)
    float* Y  = G + elems;                             // (B, N, D)

    int blk = (elems + 255) / 256;                     // 3840
    k_unshuffle<<<blk, 256, 0, stream>>>(x, xf);
    k_gproj   <<<blk, 256, 0, stream>>>(xf, g_w, g_b, G);
    k_attn    <<<BB * NN, 256, 0, stream>>>(xf, G, Y); // 16384 blocks
    k_out     <<<blk, 256, 0, stream>>>(Y, w_w, w_b, x, out);
}

// Round 3
// 277.813 us; speedup vs baseline: 64.2539x; 64.2539x over previous
//
#include <hip/hip_runtime.h>
#include <hip/hip_bf16.h>

// Problem constants (fixed by the reference):
// x: (B=4, T=5, C=3, H=128, W=128) fp32 ; R=2 ; D = T*C*R*R = 60
// xf: (B, D, N) with N = 64*64 = 4096
#define BB 4
#define TC 15        // T*C
#define DD 60
#define NN 4096
#define HH 128
#define DP 64        // d padded to MFMA K
#define KT 64        // key-tile size
#define NWAVE 4
#define QT 64        // queries per block (16 per wave)
#define NTILES (NN / KT)   // 64
#define LSTR 72      // LDS row stride in bf16 elems: 144 B = 16B-aligned, odd dword shift

typedef short s8v __attribute__((ext_vector_type(8)));   // 8 x bf16 (4 VGPRs)
typedef float f4v __attribute__((ext_vector_type(4)));   // MFMA accumulator

static __device__ __forceinline__ ushort f2bf_bits(float f) {
    __hip_bfloat16 h = __float2bfloat16(f);
    return *reinterpret_cast<ushort*>(&h);
}

// ---------------- Kernel 1: pixel-unshuffle gather  x -> xf (f32) + xf_bf (bf16) ----------------
__global__ __launch_bounds__(256) void k_unshuffle(const float* __restrict__ x,
                                                   float* __restrict__ xf,
                                                   __hip_bfloat16* __restrict__ xf_bf) {
    int idx = blockIdx.x * 256 + threadIdx.x;          // over B*D*N = 983040
    if (idx >= BB * DD * NN) return;
    int n = idx & (NN - 1);
    int d = (idx >> 12) % DD;
    int b = idx / (DD * NN);
    int oh = n >> 6, ow = n & 63;
    int c1 = d >> 2, r1 = (d >> 1) & 1, r2 = d & 1;
    float v = x[((b * TC + c1) * HH + oh * 2 + r1) * HH + ow * 2 + r2];
    xf[idx] = v;
    xf_bf[idx] = __float2bfloat16(v);
}

// ---------------- Kernel 2: G[b,o,n] = g_b[o] + sum_d g_w[o,d]*xf[b,d,n]  (bf16 out) ----------------
__global__ __launch_bounds__(256) void k_gproj(const float* __restrict__ xf,
                                               const float* __restrict__ g_w,
                                               const float* __restrict__ g_b,
                                               __hip_bfloat16* __restrict__ G_bf) {
    int idx = blockIdx.x * 256 + threadIdx.x;          // over B*D*N, n fastest
    if (idx >= BB * DD * NN) return;
    int n = idx & (NN - 1);
    int o = (idx >> 12) % DD;
    int b = idx / (DD * NN);
    const float* K = xf + b * DD * NN;
    float acc = g_b[o];
    #pragma unroll
    for (int d = 0; d < DD; ++d)
        acc += g_w[o * DD + d] * K[d * NN + n];
    G_bf[idx] = __float2bfloat16(acc);
}

// ---------------- Kernel 3: flash attention with bf16 MFMA ----------------
// Per block: one batch b, QT=64 query rows (16 per wave). Loop over 64-key tiles.
// S = Q.K^T via mfma_f32_16x16x32_bf16 (d padded to 64, zeros), online softmax in
// C/D layout (col=lane&15, row=(lane>>4)*4+reg), P staged per-wave in LDS as bf16,
// PV mfma accumulates O in f32 frags. Y written as (B, N, D) f32.
__global__ __launch_bounds__(256) void k_attn_mfma(const ushort* __restrict__ xf_bf,
                                                   const ushort* __restrict__ G_bf,
                                                   float* __restrict__ Y) {
    __shared__ ushort K_lds[KT][LSTR];            // [key][d]   (transposed stage)
    __shared__ ushort G_lds[DP][LSTR];            // [o][key]
    __shared__ ushort P_lds[NWAVE][16][LSTR];     // per-wave P tile [q][key]

    int blk = blockIdx.x;                         // b * 64 + qtile
    int b   = blk >> 6;
    int q0  = (blk & 63) * QT;
    int tid = threadIdx.x;
    int lane = tid & 63, wv = tid >> 6;
    int r = lane & 15, g = lane >> 4;

    const ushort* Xb = xf_bf + b * DD * NN;
    const ushort* Gb = G_bf + b * DD * NN;

    // Q A-fragments (2 k-blocks over d), loaded direct from global, once.
    // A slot convention: lane holds A[row=lane&15][k=(lane>>4)*8+j].
    s8v qa[2];
    int qrow = q0 + wv * 16 + r;
    #pragma unroll
    for (int kb = 0; kb < 2; ++kb)
        #pragma unroll
        for (int j = 0; j < 8; ++j) {
            int d = kb * 32 + g * 8 + j;
            qa[kb][j] = (short)((d < DD) ? Xb[d * NN + qrow] : (ushort)0);
        }

    f4v of[4];
    #pragma unroll
    for (int t = 0; t < 4; ++t) of[t] = (f4v){0.f, 0.f, 0.f, 0.f};
    float m[4], l[4];
    #pragma unroll
    for (int i = 0; i < 4; ++i) { m[i] = -1e30f; l[i] = 0.f; }

    for (int t = 0; t < NTILES; ++t) {
        int n0 = t * KT;
        // ---- stage K-tile (transposed -> [key][d], d>=60 zeroed) ----
        #pragma unroll
        for (int i = 0; i < 16; ++i) {
            int e = i * 256 + tid;
            int d = e >> 6, key = e & 63;
            K_lds[key][d] = (d < DD) ? Xb[d * NN + n0 + key] : (ushort)0;
        }
        // ---- stage G-tile ([o][key], o>=60 zeroed), u32-vectorized ----
        #pragma unroll
        for (int i = 0; i < 8; ++i) {
            int e = i * 256 + tid;
            int o = e >> 5, kp = e & 31;
            uint v = (o < DD) ? *(const uint*)(Gb + o * NN + n0 + 2 * kp) : 0u;
            *(uint*)&G_lds[o][2 * kp] = v;
        }
        __syncthreads();

        // ---- S = Q.K^T : 4 key sub-tiles x 2 d-blocks ----
        f4v sf[4];
        #pragma unroll
        for (int kt2 = 0; kt2 < 4; ++kt2) sf[kt2] = (f4v){0.f, 0.f, 0.f, 0.f};
        #pragma unroll
        for (int kt2 = 0; kt2 < 4; ++kt2)
            #pragma unroll
            for (int kb = 0; kb < 2; ++kb) {
                s8v bfrag = *(const s8v*)&K_lds[kt2 * 16 + r][kb * 32 + g * 8];
                sf[kt2] = __builtin_amdgcn_mfma_f32_16x16x32_bf16(qa[kb], bfrag, sf[kt2], 0, 0, 0);
            }

        // ---- online softmax over this tile's 64 cols (rows = 4g+reg) ----
        float pmax[4], mn[4], sc[4], psum[4];
        #pragma unroll
        for (int reg = 0; reg < 4; ++reg) {
            float v = fmaxf(fmaxf(sf[0][reg], sf[1][reg]), fmaxf(sf[2][reg], sf[3][reg]));
            #pragma unroll
            for (int off = 1; off < 16; off <<= 1) v = fmaxf(v, __shfl_xor(v, off));
            pmax[reg] = v;
            mn[reg] = fmaxf(m[reg], pmax[reg]);
            sc[reg] = __expf(m[reg] - mn[reg]);
            psum[reg] = 0.f;
        }
        #pragma unroll
        for (int kt2 = 0; kt2 < 4; ++kt2)
            #pragma unroll
            for (int reg = 0; reg < 4; ++reg) {
                float p = __expf(sf[kt2][reg] - mn[reg]);
                psum[reg] += p;
                P_lds[wv][4 * g + reg][kt2 * 16 + r] = f2bf_bits(p);
            }
        #pragma unroll
        for (int reg = 0; reg < 4; ++reg) {
            float v = psum[reg];
            #pragma unroll
            for (int off = 1; off < 16; off <<= 1) v += __shfl_xor(v, off);
            l[reg] = l[reg] * sc[reg] + v;
            m[reg] = mn[reg];
        }
        #pragma unroll
        for (int ot = 0; ot < 4; ++ot)
            #pragma unroll
            for (int reg = 0; reg < 4; ++reg) of[ot][reg] *= sc[reg];

        // ---- O += P . G^T : A=P (wave-private LDS), B=G_lds ----
        #pragma unroll
        for (int kb = 0; kb < 2; ++kb) {
            s8v pa = *(const s8v*)&P_lds[wv][r][kb * 32 + g * 8];
            #pragma unroll
            for (int ot = 0; ot < 4; ++ot) {
                s8v bfrag = *(const s8v*)&G_lds[ot * 16 + r][kb * 32 + g * 8];
                of[ot] = __builtin_amdgcn_mfma_f32_16x16x32_bf16(pa, bfrag, of[ot], 0, 0, 0);
            }
        }
        __syncthreads();   // all waves done with K_lds/G_lds before next stage
    }

    // ---- epilogue: Y[b][q][o] = O/l ----
    #pragma unroll
    for (int ot = 0; ot < 4; ++ot) {
        int o = ot * 16 + r;
        if (o < DD) {
            #pragma unroll
            for (int reg = 0; reg < 4; ++reg) {
                int q = q0 + wv * 16 + 4 * g + reg;
                Y[(b * NN + q) * DD + o] = of[ot][reg] / l[reg];
            }
        }
    }
}

// ---------------- Kernel 4: out = pixel_shuffle(w_w . Y + w_b) + x ----------------
__global__ __launch_bounds__(256) void k_out(const float* __restrict__ Y,
                                             const float* __restrict__ w_w,
                                             const float* __restrict__ w_b,
                                             const float* __restrict__ x,
                                             float* __restrict__ out) {
    int idx = blockIdx.x * 256 + threadIdx.x;          // over B*D*N, n fastest
    if (idx >= BB * DD * NN) return;
    int n = idx & (NN - 1);
    int o = (idx >> 12) % DD;
    int b = idx / (DD * NN);
    const float* Yb = Y + b * NN * DD;
    float acc = w_b[o];
    #pragma unroll
    for (int d = 0; d < DD; ++d)
        acc += w_w[o * DD + d] * Yb[n * DD + d];
    int oh = n >> 6, ow = n & 63;
    int c1 = o >> 2, r1 = (o >> 1) & 1, r2 = o & 1;
    int xi = ((b * TC + c1) * HH + oh * 2 + r1) * HH + ow * 2 + r2;
    out[xi] = acc + x[xi];
}

extern "C" void kernel_launch(void* const* d_in, const int* in_sizes, int n_in,
                              void* d_out, int out_size, void* d_ws, size_t ws_size,
                              hipStream_t stream) {
    const float* x   = (const float*)d_in[0];
    const float* g_w = (const float*)d_in[1];
    const float* g_b = (const float*)d_in[2];
    const float* w_w = (const float*)d_in[3];
    const float* w_b = (const float*)d_in[4];
    float* out = (float*)d_out;

    const int elems = BB * DD * NN;                    // 983040
    char* ws = (char*)d_ws;
    float*          xf    = (float*)ws;                          // 3.93 MB
    float*          Yv    = (float*)(ws + elems * 4);            // 3.93 MB
    __hip_bfloat16* xf_bf = (__hip_bfloat16*)(ws + elems * 8);   // 1.97 MB
    __hip_bfloat16* G_bf  = (__hip_bfloat16*)(ws + elems * 10);  // 1.97 MB

    int blk = (elems + 255) / 256;                     // 3840
    k_unshuffle<<<blk, 256, 0, stream>>>(x, xf, xf_bf);
    k_gproj   <<<blk, 256, 0, stream>>>(xf, g_w, g_b, G_bf);
    k_attn_mfma<<<BB * (NN / QT), 256, 0, stream>>>((const ushort*)xf_bf,
                                                    (const ushort*)G_bf, Yv);
    k_out     <<<blk, 256, 0, stream>>>(Yv, w_w, w_b, x, out);
}

// Round 4
// 127.280 us; speedup vs baseline: 140.2467x; 2.1827x over previous
//
#include <hip/hip_runtime.h>
#include <hip/hip_bf16.h>

// Problem constants (fixed by the reference):
// x: (B=4, T=5, C=3, H=128, W=128) fp32 ; R=2 ; D = T*C*R*R = 60
// xf: (B, D, N) with N = 64*64 = 4096
#define BB 4
#define TC 15        // T*C
#define DD 60
#define NN 4096
#define HH 128
#define DP 64        // d padded to MFMA K
#define KT 64        // key-tile size
#define NWAVE 4
#define QT 64        // queries per block (16 per wave)
#define NTILES (NN / KT)   // 64
#define NSPLIT 4
#define LSTR 72      // LDS row stride in bf16 elems (144 B)

typedef short s8v __attribute__((ext_vector_type(8)));   // 8 x bf16 (4 VGPRs)
typedef float f4v __attribute__((ext_vector_type(4)));   // MFMA accumulator

static __device__ __forceinline__ ushort f2bf_bits(float f) {
    __hip_bfloat16 h = __float2bfloat16(f);
    return *reinterpret_cast<ushort*>(&h);
}

// ---------------- Kernel 1: pixel-unshuffle gather  x -> xf (f32, (B,D,N)) ----------------
__global__ __launch_bounds__(256) void k_unshuffle(const float* __restrict__ x,
                                                   float* __restrict__ xf) {
    int idx = blockIdx.x * 256 + threadIdx.x;          // over B*D*N = 983040
    if (idx >= BB * DD * NN) return;
    int n = idx & (NN - 1);
    int d = (idx >> 12) % DD;
    int b = idx / (DD * NN);
    int oh = n >> 6, ow = n & 63;
    int c1 = d >> 2, r1 = (d >> 1) & 1, r2 = d & 1;
    xf[idx] = x[((b * TC + c1) * HH + oh * 2 + r1) * HH + ow * 2 + r2];
}

// ---------------- Kernel 1b: transpose to xf_t (B, N, 64) bf16, d-padded with zeros ----------------
__global__ __launch_bounds__(256) void k_transpose(const float* __restrict__ xf,
                                                   ushort* __restrict__ xf_t) {
    int n = blockIdx.x * 256 + threadIdx.x;            // over B*N = 16384
    int b = n >> 12, nn = n & (NN - 1);
    const float* src = xf + b * DD * NN + nn;
    ushort row[DP];
    #pragma unroll
    for (int d = 0; d < DD; ++d) row[d] = f2bf_bits(src[d * NN]);
    #pragma unroll
    for (int d = DD; d < DP; ++d) row[d] = 0;
    ushort* dst = xf_t + (size_t)n * DP;
    #pragma unroll
    for (int j = 0; j < 8; ++j)
        *(s8v*)&dst[j * 8] = *(const s8v*)&row[j * 8];
}

// ---------------- Kernel 2: G[b,o,n] = g_b[o] + sum_d g_w[o,d]*xf[b,d,n]  (bf16 out, (B,D,N)) ----------------
__global__ __launch_bounds__(256) void k_gproj(const float* __restrict__ xf,
                                               const float* __restrict__ g_w,
                                               const float* __restrict__ g_b,
                                               __hip_bfloat16* __restrict__ G_bf) {
    int idx = blockIdx.x * 256 + threadIdx.x;          // over B*D*N, n fastest
    if (idx >= BB * DD * NN) return;
    int n = idx & (NN - 1);
    int o = (idx >> 12) % DD;
    int b = idx / (DD * NN);
    const float* K = xf + b * DD * NN;
    float acc = g_b[o];
    #pragma unroll
    for (int d = 0; d < DD; ++d)
        acc += g_w[o * DD + d] * K[d * NN + n];
    G_bf[idx] = __float2bfloat16(acc);
}

// ---------------- Kernel 3: flash attention with bf16 MFMA, optional split-K ----------------
// grid = (s * BB + b) * 64 + qtile   (NS splits of 16 key-tiles each)
// NS==1: writes normalized Y (B,N,DD).  NS>1: writes O_part (unnormalized) + (m,l) per row.
template <int NS>
__global__ __launch_bounds__(256) void k_attn_mfma(const ushort* __restrict__ xf_t,
                                                   const ushort* __restrict__ G_bf,
                                                   float* __restrict__ Y,
                                                   float* __restrict__ O_part,
                                                   float* __restrict__ ml_part) {
    __shared__ ushort K_lds[KT][LSTR];            // [key][d]
    __shared__ ushort G_lds[DP][LSTR];            // [o][key]
    __shared__ ushort P_lds[NWAVE][16][LSTR];     // per-wave P tile [q][key]

    int blk = blockIdx.x;
    int s   = blk / (BB * 64);
    int rem = blk % (BB * 64);
    int b   = rem >> 6;
    int q0  = (rem & 63) * QT;
    int tid = threadIdx.x;
    int lane = tid & 63, wv = tid >> 6;
    int r = lane & 15, g = lane >> 4;

    const ushort* Xt = xf_t + (size_t)b * NN * DP;    // (N, 64) bf16
    const ushort* Gb = G_bf + (size_t)b * DD * NN;    // (D, N) bf16

    // Q A-fragments: lane holds A[row=lane&15][k=(lane>>4)*8+j]; direct b128 loads.
    int qrow = q0 + wv * 16 + r;
    s8v qa[2];
    #pragma unroll
    for (int kb = 0; kb < 2; ++kb)
        qa[kb] = *(const s8v*)&Xt[qrow * DP + kb * 32 + g * 8];

    f4v of[4];
    #pragma unroll
    for (int t = 0; t < 4; ++t) of[t] = (f4v){0.f, 0.f, 0.f, 0.f};
    float m[4], l[4];
    #pragma unroll
    for (int i = 0; i < 4; ++i) { m[i] = -1e30f; l[i] = 0.f; }

    const int t0 = s * (NTILES / NS);
    for (int t = t0; t < t0 + NTILES / NS; ++t) {
        int n0 = t * KT;
        // ---- stage K-tile [key][d] via b128 (2 iters x 256 threads x 16B) ----
        #pragma unroll
        for (int i = 0; i < 2; ++i) {
            int e = i * 256 + tid;
            int key = e >> 3, j = e & 7;
            *(s8v*)&K_lds[key][j * 8] = *(const s8v*)&Xt[(n0 + key) * DP + j * 8];
        }
        // ---- stage G-tile [o][key] via b128, o>=60 zeroed ----
        #pragma unroll
        for (int i = 0; i < 2; ++i) {
            int e = i * 256 + tid;
            int o = e >> 3, j = e & 7;
            s8v v = (o < DD) ? *(const s8v*)&Gb[o * NN + n0 + j * 8]
                             : (s8v){0, 0, 0, 0, 0, 0, 0, 0};
            *(s8v*)&G_lds[o][j * 8] = v;
        }
        __syncthreads();

        // ---- S = Q.K^T : 4 key sub-tiles x 2 d-blocks ----
        f4v sf[4];
        #pragma unroll
        for (int kt2 = 0; kt2 < 4; ++kt2) sf[kt2] = (f4v){0.f, 0.f, 0.f, 0.f};
        #pragma unroll
        for (int kt2 = 0; kt2 < 4; ++kt2)
            #pragma unroll
            for (int kb = 0; kb < 2; ++kb) {
                s8v bfrag = *(const s8v*)&K_lds[kt2 * 16 + r][kb * 32 + g * 8];
                sf[kt2] = __builtin_amdgcn_mfma_f32_16x16x32_bf16(qa[kb], bfrag, sf[kt2], 0, 0, 0);
            }

        // ---- online softmax (C/D layout: col=r -> key, row=4g+reg -> query) ----
        float pmax[4], mn[4], sc[4], psum[4];
        #pragma unroll
        for (int reg = 0; reg < 4; ++reg) {
            float v = fmaxf(fmaxf(sf[0][reg], sf[1][reg]), fmaxf(sf[2][reg], sf[3][reg]));
            #pragma unroll
            for (int off = 1; off < 16; off <<= 1) v = fmaxf(v, __shfl_xor(v, off));
            pmax[reg] = v;
            mn[reg] = fmaxf(m[reg], pmax[reg]);
            sc[reg] = __expf(m[reg] - mn[reg]);
            psum[reg] = 0.f;
        }
        #pragma unroll
        for (int kt2 = 0; kt2 < 4; ++kt2)
            #pragma unroll
            for (int reg = 0; reg < 4; ++reg) {
                float p = __expf(sf[kt2][reg] - mn[reg]);
                psum[reg] += p;
                P_lds[wv][4 * g + reg][kt2 * 16 + r] = f2bf_bits(p);
            }
        #pragma unroll
        for (int reg = 0; reg < 4; ++reg) {
            float v = psum[reg];
            #pragma unroll
            for (int off = 1; off < 16; off <<= 1) v += __shfl_xor(v, off);
            l[reg] = l[reg] * sc[reg] + v;
            m[reg] = mn[reg];
        }
        #pragma unroll
        for (int ot = 0; ot < 4; ++ot)
            #pragma unroll
            for (int reg = 0; reg < 4; ++reg) of[ot][reg] *= sc[reg];

        // ---- O += P . G^T ----
        #pragma unroll
        for (int kb = 0; kb < 2; ++kb) {
            s8v pa = *(const s8v*)&P_lds[wv][r][kb * 32 + g * 8];
            #pragma unroll
            for (int ot = 0; ot < 4; ++ot) {
                s8v bfrag = *(const s8v*)&G_lds[ot * 16 + r][kb * 32 + g * 8];
                of[ot] = __builtin_amdgcn_mfma_f32_16x16x32_bf16(pa, bfrag, of[ot], 0, 0, 0);
            }
        }
        __syncthreads();
    }

    // ---- epilogue ----
    if (NS == 1) {
        #pragma unroll
        for (int ot = 0; ot < 4; ++ot) {
            int o = ot * 16 + r;
            if (o < DD) {
                #pragma unroll
                for (int reg = 0; reg < 4; ++reg) {
                    int q = q0 + wv * 16 + 4 * g + reg;
                    Y[((size_t)b * NN + q) * DD + o] = of[ot][reg] / l[reg];
                }
            }
        }
    } else {
        float* Ob = O_part + ((size_t)(s * BB + b) * NN) * DD;
        #pragma unroll
        for (int ot = 0; ot < 4; ++ot) {
            int o = ot * 16 + r;
            if (o < DD) {
                #pragma unroll
                for (int reg = 0; reg < 4; ++reg) {
                    int q = q0 + wv * 16 + 4 * g + reg;
                    Ob[(size_t)q * DD + o] = of[ot][reg];
                }
            }
        }
        if (r == 0) {
            #pragma unroll
            for (int reg = 0; reg < 4; ++reg) {
                int q = q0 + wv * 16 + 4 * g + reg;
                float* ml = ml_part + ((size_t)(s * BB + b) * NN + q) * 2;
                ml[0] = m[reg];
                ml[1] = l[reg];
            }
        }
    }
}

// ---------------- Kernel 3b: combine split-K partials -> Y (B,N,DD) ----------------
__global__ __launch_bounds__(256) void k_combine(const float* __restrict__ O_part,
                                                 const float* __restrict__ ml_part,
                                                 float* __restrict__ Y) {
    int idx = blockIdx.x * 256 + threadIdx.x;          // over B*N*DD, o fastest
    if (idx >= BB * NN * DD) return;
    int o = idx % DD;
    int q = (idx / DD) & (NN - 1);
    int b = idx / (DD * NN);
    float ms[NSPLIT], ls[NSPLIT];
    float M = -1e30f;
    #pragma unroll
    for (int s = 0; s < NSPLIT; ++s) {
        const float* ml = ml_part + ((size_t)(s * BB + b) * NN + q) * 2;
        ms[s] = ml[0]; ls[s] = ml[1];
        M = fmaxf(M, ms[s]);
    }
    float L = 0.f, acc = 0.f;
    #pragma unroll
    for (int s = 0; s < NSPLIT; ++s) {
        float w = __expf(ms[s] - M);
        L += w * ls[s];
        acc += w * O_part[((size_t)(s * BB + b) * NN + q) * DD + o];
    }
    Y[idx] = acc / L;
}

// ---------------- Kernel 4: out = pixel_shuffle(w_w . Y + w_b) + x ----------------
__global__ __launch_bounds__(256) void k_out(const float* __restrict__ Y,
                                             const float* __restrict__ w_w,
                                             const float* __restrict__ w_b,
                                             const float* __restrict__ x,
                                             float* __restrict__ out) {
    int idx = blockIdx.x * 256 + threadIdx.x;          // over B*D*N, n fastest
    if (idx >= BB * DD * NN) return;
    int n = idx & (NN - 1);
    int o = (idx >> 12) % DD;
    int b = idx / (DD * NN);
    const float* Yb = Y + (size_t)b * NN * DD;
    float acc = w_b[o];
    #pragma unroll
    for (int d = 0; d < DD; ++d)
        acc += w_w[o * DD + d] * Yb[n * DD + d];
    int oh = n >> 6, ow = n & 63;
    int c1 = o >> 2, r1 = (o >> 1) & 1, r2 = o & 1;
    int xi = ((b * TC + c1) * HH + oh * 2 + r1) * HH + ow * 2 + r2;
    out[xi] = acc + x[xi];
}

extern "C" void kernel_launch(void* const* d_in, const int* in_sizes, int n_in,
                              void* d_out, int out_size, void* d_ws, size_t ws_size,
                              hipStream_t stream) {
    const float* x   = (const float*)d_in[0];
    const float* g_w = (const float*)d_in[1];
    const float* g_b = (const float*)d_in[2];
    const float* w_w = (const float*)d_in[3];
    const float* w_b = (const float*)d_in[4];
    float* out = (float*)d_out;

    const size_t elems = (size_t)BB * DD * NN;         // 983040
    const size_t rows  = (size_t)BB * NN;              // 16384
    char* ws = (char*)d_ws;
    size_t off = 0;
    float*  xf   = (float*)(ws + off);  off += elems * 4;          // (B,D,N) f32; later aliased as Y
    ushort* xf_t = (ushort*)(ws + off); off += rows * DP * 2;      // (B,N,64) bf16
    __hip_bfloat16* G_bf = (__hip_bfloat16*)(ws + off); off += elems * 2;  // (B,D,N) bf16
    size_t base_need = off;
    float* O_part  = (float*)(ws + off); off += (size_t)NSPLIT * elems * 4;
    float* ml_part = (float*)(ws + off); off += (size_t)NSPLIT * rows * 2 * 4;
    size_t split_need = off;
    float* Y = xf;   // alias: xf (f32) is dead after k_gproj/k_transpose

    int blk = (int)((elems + 255) / 256);              // 3840
    k_unshuffle<<<blk, 256, 0, stream>>>(x, xf);
    k_transpose<<<rows / 256, 256, 0, stream>>>(xf, xf_t);
    k_gproj    <<<blk, 256, 0, stream>>>(xf, g_w, g_b, G_bf);

    if (ws_size >= split_need) {
        k_attn_mfma<NSPLIT><<<NSPLIT * BB * (NN / QT), 256, 0, stream>>>(
            xf_t, (const ushort*)G_bf, Y, O_part, ml_part);
        k_combine<<<blk, 256, 0, stream>>>(O_part, ml_part, Y);
    } else {
        (void)base_need;
        k_attn_mfma<1><<<BB * (NN / QT), 256, 0, stream>>>(
            xf_t, (const ushort*)G_bf, Y, nullptr, nullptr);
    }
    k_out<<<blk, 256, 0, stream>>>(Y, w_w, w_b, x, out);
}

// Round 5
// 108.483 us; speedup vs baseline: 164.5478x; 1.1733x over previous
//
#include <hip/hip_runtime.h>
#include <hip/hip_bf16.h>

// x: (B=4, T=5, C=3, H=128, W=128) fp32 ; R=2 ; D = 60 ; N = 4096
#define BB 4
#define TC 15
#define DD 60
#define NN 4096
#define HH 128
#define DP 64
#define KT 64
#define NWAVE 4
#define QT 64
#define NTILES 64
#define NSPLIT 4
#define L2E 1.4426950408889634f

typedef short s8v __attribute__((ext_vector_type(8)));   // 8 x bf16
typedef float f4v __attribute__((ext_vector_type(4)));
typedef float f2v __attribute__((ext_vector_type(2)));

static __device__ __forceinline__ ushort f2bf_bits(float f) {
    __hip_bfloat16 h = __float2bfloat16(f);
    return *reinterpret_cast<ushort*>(&h);
}

// ---------- K1: pixel-unshuffle -> xf_bf (B,D,N) bf16, vec2 along n ----------
__global__ __launch_bounds__(256) void k_unshuf_bf(const float* __restrict__ x,
                                                   ushort* __restrict__ xf_bf) {
    int u = blockIdx.x * 256 + threadIdx.x;            // over elems/2
    int idx = u * 2;
    int n = idx & (NN - 1);
    int d = (idx >> 12) % DD;
    int b = idx / (DD * NN);
    int oh = n >> 6, ow = n & 63;
    int c1 = d >> 2, r1 = (d >> 1) & 1, r2 = d & 1;
    const float* xs = x + ((b * TC + c1) * HH + oh * 2 + r1) * HH + ow * 2 + r2;
    uint pack = (uint)f2bf_bits(xs[0]) | ((uint)f2bf_bits(xs[2]) << 16);
    *(uint*)&xf_bf[idx] = pack;
}

// ---------- K1b: transpose -> xf_t (B,N,64) bf16 (d-padded), b128 writes ----------
__global__ __launch_bounds__(256) void k_transpose(const ushort* __restrict__ xf_bf,
                                                   ushort* __restrict__ xf_t) {
    int e = blockIdx.x * 256 + threadIdx.x;            // over B*N*8 = 131072
    int j = e & 7;
    int ng = e >> 3;                                   // b*N + n
    int b = ng >> 12, n = ng & (NN - 1);
    const ushort* src = xf_bf + b * DD * NN + n;
    ushort v[8];
    #pragma unroll
    for (int jj = 0; jj < 8; ++jj) {
        int d = j * 8 + jj;
        v[jj] = (d < DD) ? src[d * NN] : (ushort)0;
    }
    *(s8v*)&xf_t[(size_t)ng * DP + j * 8] = *(s8v*)v;
}

// ---------- K2: G (B,D,N) bf16 = g_w . xf + g_b, vec2 along n ----------
__global__ __launch_bounds__(256) void k_gproj(const ushort* __restrict__ xf_bf,
                                               const float* __restrict__ g_w,
                                               const float* __restrict__ g_b,
                                               ushort* __restrict__ G_bf) {
    int u = blockIdx.x * 256 + threadIdx.x;            // over elems/2
    int idx = u * 2;
    int n = idx & (NN - 1);
    int o = (idx >> 12) % DD;                          // block-uniform
    int b = idx / (DD * NN);
    const ushort* X = xf_bf + b * DD * NN;
    float a0 = g_b[o], a1 = a0;
    #pragma unroll
    for (int d = 0; d < DD; ++d) {
        uint w = *(const uint*)&X[d * NN + n];
        float gw = g_w[o * DD + d];
        a0 += gw * __uint_as_float(w << 16);
        a1 += gw * __uint_as_float(w & 0xFFFF0000u);
    }
    uint pack = (uint)f2bf_bits(a0) | ((uint)f2bf_bits(a1) << 16);
    *(uint*)&G_bf[idx] = pack;
}

// ---------- K3: flash attention, bf16 MFMA, split-K, reg-prefetch, XOR-swizzled LDS ----------
// l folded into PV via G row 60 == 1.0 (o=60 accumulator column is the running denominator).
template <int NS>
__global__ __launch_bounds__(256) void k_attn(const ushort* __restrict__ xf_t,
                                              const ushort* __restrict__ G_bf,
                                              float* __restrict__ Y,       // NS==1
                                              float* __restrict__ O_part,  // NS>1: (s,b,64,N)
                                              float* __restrict__ ml) {    // NS>1: (s,b,N)
    __shared__ char K_lds[KT * 128];
    __shared__ char G_lds[DP * 128];
    __shared__ char P_lds[NWAVE][16 * 128];

    int p = blockIdx.x;
    int s, b, q0;
    if (NS == NSPLIT) {
        // XCD-aware: xcd = p&7 owns batch b = xcd>>1 (4MB working set = one L2)
        int xcd = p & 7, slot = p >> 3;
        b = xcd >> 1;
        s = 2 * (xcd & 1) + (slot >> 6);
        q0 = (slot & 63) * QT;
    } else {
        s = 0;
        b = p >> 6;
        q0 = (p & 63) * QT;
    }
    int tid = threadIdx.x;
    int lane = tid & 63, wv = tid >> 6;
    int r = lane & 15, g = lane >> 4;

    const ushort* Xt = xf_t + (size_t)b * NN * DP;
    const ushort* Gb = G_bf + (size_t)b * DD * NN;

    int qrow = q0 + wv * 16 + r;
    s8v qa[2];
    qa[0] = *(const s8v*)&Xt[(size_t)qrow * DP + g * 8];
    qa[1] = *(const s8v*)&Xt[(size_t)qrow * DP + 32 + g * 8];

    f4v of[4];
    #pragma unroll
    for (int i = 0; i < 4; ++i) of[i] = (f4v){0.f, 0.f, 0.f, 0.f};
    float m[4] = {-1e30f, -1e30f, -1e30f, -1e30f};

    // staging geometry: e in [0,512), row = e>>3, 16B unit j = e&7
    const int e0 = tid, e1 = 256 + tid;
    const int kr0 = e0 >> 3, kj0 = e0 & 7;
    const int kr1 = e1 >> 3, kj1 = e1 & 7;
    const int kw0 = (kr0 * 128 + kj0 * 16) ^ ((kr0 & 7) << 4);
    const int kw1 = (kr1 * 128 + kj1 * 16) ^ ((kr1 & 7) << 4);

    const s8v ones8 = {(short)0x3F80, (short)0x3F80, (short)0x3F80, (short)0x3F80,
                       (short)0x3F80, (short)0x3F80, (short)0x3F80, (short)0x3F80};
    const s8v zero8 = {0, 0, 0, 0, 0, 0, 0, 0};
    s8v kp0, kp1, gp0, gp1;

    auto stage_regs = [&](int t) {
        int n0 = t * KT;
        kp0 = *(const s8v*)&Xt[(size_t)(n0 + kr0) * DP + kj0 * 8];
        kp1 = *(const s8v*)&Xt[(size_t)(n0 + kr1) * DP + kj1 * 8];
        gp0 = *(const s8v*)&Gb[(size_t)kr0 * NN + n0 + kj0 * 8];          // rows 0..31 < 60
        gp1 = (kr1 < DD) ? *(const s8v*)&Gb[(size_t)kr1 * NN + n0 + kj1 * 8]
                         : (kr1 == DD ? ones8 : zero8);
    };
    auto lds_write = [&]() {
        *(s8v*)(K_lds + kw0) = kp0;
        *(s8v*)(K_lds + kw1) = kp1;
        *(s8v*)(G_lds + kw0) = gp0;
        *(s8v*)(G_lds + kw1) = gp1;
    };

    const int t0 = s * (NTILES / NS);
    const int tend = t0 + NTILES / NS;
    char* Pw = P_lds[wv];

    stage_regs(t0);
    lds_write();
    __syncthreads();

    #pragma unroll 1
    for (int t = t0; t < tend; ++t) {
        bool more = (t + 1 < tend);
        if (more) stage_regs(t + 1);          // loads in flight during compute

        // ---- S = Q.K^T ----
        f4v sf[4];
        #pragma unroll
        for (int i = 0; i < 4; ++i) sf[i] = (f4v){0.f, 0.f, 0.f, 0.f};
        #pragma unroll
        for (int kt2 = 0; kt2 < 4; ++kt2)
            #pragma unroll
            for (int kb = 0; kb < 2; ++kb) {
                int off = (((kt2 * 16 + r) * 128) + kb * 64 + g * 16) ^ ((r & 7) << 4);
                s8v bf = *(const s8v*)(K_lds + off);
                sf[kt2] = __builtin_amdgcn_mfma_f32_16x16x32_bf16(qa[kb], bf, sf[kt2], 0, 0, 0);
            }

        // ---- row max (per reg; uniform within 16-lane group after reduce) ----
        float pmax[4];
        #pragma unroll
        for (int reg = 0; reg < 4; ++reg) {
            float v = fmaxf(fmaxf(sf[0][reg], sf[1][reg]), fmaxf(sf[2][reg], sf[3][reg]));
            #pragma unroll
            for (int off = 1; off < 16; off <<= 1) v = fmaxf(v, __shfl_xor(v, off));
            pmax[reg] = v;
        }
        bool ok = (pmax[0] <= m[0] + 8.f) && (pmax[1] <= m[1] + 8.f) &&
                  (pmax[2] <= m[2] + 8.f) && (pmax[3] <= m[3] + 8.f);
        if (!__all(ok)) {                      // rescale path (rare after first tile)
            #pragma unroll
            for (int reg = 0; reg < 4; ++reg) {
                float mn = fmaxf(m[reg], pmax[reg]);
                float sc = __builtin_exp2f((m[reg] - mn) * L2E);
                m[reg] = mn;
                of[0][reg] *= sc; of[1][reg] *= sc; of[2][reg] *= sc; of[3][reg] *= sc;
            }
        }

        // ---- P = 2^((S - m)*log2e), bf16 into wave-private swizzled LDS ----
        float nm[4];
        #pragma unroll
        for (int reg = 0; reg < 4; ++reg) nm[reg] = -m[reg] * L2E;
        #pragma unroll
        for (int kt2 = 0; kt2 < 4; ++kt2)
            #pragma unroll
            for (int reg = 0; reg < 4; ++reg) {
                float pv = __builtin_exp2f(fmaf(sf[kt2][reg], L2E, nm[reg]));
                int row = 4 * g + reg;
                int boff = ((row * 128) + kt2 * 32 + 2 * r) ^ ((row & 7) << 4);
                *(ushort*)(Pw + boff) = f2bf_bits(pv);
            }

        // ---- O += P . G^T  (col 60 accumulates the denominator) ----
        #pragma unroll
        for (int kb = 0; kb < 2; ++kb) {
            int poff = ((r * 128) + kb * 64 + g * 16) ^ ((r & 7) << 4);
            s8v pa = *(const s8v*)(Pw + poff);
            #pragma unroll
            for (int ot = 0; ot < 4; ++ot) {
                int goff = (((ot * 16 + r) * 128) + kb * 64 + g * 16) ^ ((r & 7) << 4);
                s8v gf = *(const s8v*)(G_lds + goff);
                of[ot] = __builtin_amdgcn_mfma_f32_16x16x32_bf16(pa, gf, of[ot], 0, 0, 0);
            }
        }

        if (more) {
            __syncthreads();
            lds_write();
            __syncthreads();
        }
    }

    int qb = q0 + wv * 16 + 4 * g;
    if (NS == 1) {
        float linv[4];
        #pragma unroll
        for (int reg = 0; reg < 4; ++reg)
            linv[reg] = 1.0f / __shfl(of[3][reg], 12, 16);   // o=60 column holds l
        #pragma unroll
        for (int ot = 0; ot < 4; ++ot) {
            int o = ot * 16 + r;
            if (o < DD) {
                f4v v;
                #pragma unroll
                for (int reg = 0; reg < 4; ++reg) v[reg] = of[ot][reg] * linv[reg];
                *(f4v*)&Y[((size_t)(b * DD + o)) * NN + qb] = v;
            }
        }
    } else {
        float* Ob = O_part + ((size_t)(s * BB + b) * DP) * NN;
        #pragma unroll
        for (int ot = 0; ot < 4; ++ot) {
            int o = ot * 16 + r;
            *(f4v*)&Ob[(size_t)o * NN + qb] = of[ot];        // coalesced 64B per r-group
        }
        if (r == 0) {
            #pragma unroll
            for (int reg = 0; reg < 4; ++reg)
                ml[(size_t)(s * BB + b) * NN + qb + reg] = m[reg];
        }
    }
}

// ---------- K3b: combine split partials -> Y (B,D,N), vec2 ----------
__global__ __launch_bounds__(256) void k_combine(const float* __restrict__ O_part,
                                                 const float* __restrict__ ml,
                                                 float* __restrict__ Y) {
    int u = blockIdx.x * 256 + threadIdx.x;            // over elems/2
    int idx = u * 2;
    int n = idx & (NN - 1);
    int o = (idx >> 12) % DD;
    int b = idx / (DD * NN);
    f2v mv[NSPLIT];
    f2v M = {-1e30f, -1e30f};
    #pragma unroll
    for (int s = 0; s < NSPLIT; ++s) {
        mv[s] = *(const f2v*)&ml[(size_t)(s * BB + b) * NN + n];
        M[0] = fmaxf(M[0], mv[s][0]);
        M[1] = fmaxf(M[1], mv[s][1]);
    }
    f2v acc = {0.f, 0.f}, L = {0.f, 0.f};
    #pragma unroll
    for (int s = 0; s < NSPLIT; ++s) {
        const float* Ob = O_part + ((size_t)(s * BB + b) * DP) * NN + n;
        f2v w = {__builtin_exp2f((mv[s][0] - M[0]) * L2E),
                 __builtin_exp2f((mv[s][1] - M[1]) * L2E)};
        f2v ov = *(const f2v*)&Ob[(size_t)o * NN];
        f2v lv = *(const f2v*)&Ob[(size_t)DD * NN];
        acc[0] += w[0] * ov[0]; acc[1] += w[1] * ov[1];
        L[0]   += w[0] * lv[0]; L[1]   += w[1] * lv[1];
    }
    f2v y = {acc[0] / L[0], acc[1] / L[1]};
    *(f2v*)&Y[idx] = y;
}

// ---------- K4: out = pixel_shuffle(w_w.Y + w_b) + x, pixel-major, vec2 over w ----------
__global__ __launch_bounds__(256) void k_out(const float* __restrict__ Y,
                                             const float* __restrict__ w_w,
                                             const float* __restrict__ w_b,
                                             const float* __restrict__ x,
                                             float* __restrict__ out) {
    __shared__ float ww[DD * DD];
    __shared__ float wb[DD];
    for (int i = threadIdx.x; i < DD * DD; i += 256) ww[i] = w_w[i];
    if (threadIdx.x < DD) wb[threadIdx.x] = w_b[threadIdx.x];
    __syncthreads();
    int u = blockIdx.x * 256 + threadIdx.x;            // over B*TC*H*(W/2)
    int w2 = u & 63;
    int h = (u >> 6) & 127;
    int rest = u >> 13;
    int c1 = rest % TC;
    int b = rest / TC;
    int o0 = c1 * 4 + (h & 1) * 2;                     // wave-uniform
    int n = ((h >> 1) << 6) + w2;
    const float* Yb = Y + (size_t)b * DD * NN + n;
    float a0 = wb[o0], a1 = wb[o0 + 1];
    #pragma unroll
    for (int d = 0; d < DD; ++d) {
        float y = Yb[(size_t)d * NN];
        a0 += ww[o0 * DD + d] * y;
        a1 += ww[(o0 + 1) * DD + d] * y;
    }
    size_t xi = ((size_t)(b * TC + c1) * HH + h) * HH + 2 * w2;
    f2v xv = *(const f2v*)&x[xi];
    f2v res = {a0 + xv[0], a1 + xv[1]};
    *(f2v*)&out[xi] = res;
}

extern "C" void kernel_launch(void* const* d_in, const int* in_sizes, int n_in,
                              void* d_out, int out_size, void* d_ws, size_t ws_size,
                              hipStream_t stream) {
    const float* x   = (const float*)d_in[0];
    const float* g_w = (const float*)d_in[1];
    const float* g_b = (const float*)d_in[2];
    const float* w_w = (const float*)d_in[3];
    const float* w_b = (const float*)d_in[4];
    float* out = (float*)d_out;

    char* ws = (char*)d_ws;
    ushort* xf_bf  = (ushort*)ws;                      // 1,966,080 B
    ushort* xf_t   = (ushort*)(ws + 1966080);          // 2,097,152 B
    ushort* G_bf   = (ushort*)(ws + 4063232);          // 1,966,080 B
    float*  O_part = (float*)(ws + 6029312);           // 16,777,216 B (s,b,64,N)
    float*  mlbuf  = (float*)(ws + 22806528);          // 262,144 B -> total 23,068,672
    const size_t SPLIT_NEED = 23068672;

    k_unshuf_bf<<<1920, 256, 0, stream>>>(x, xf_bf);
    k_transpose<<<512, 256, 0, stream>>>(xf_bf, xf_t);
    k_gproj<<<1920, 256, 0, stream>>>(xf_bf, g_w, g_b, G_bf);

    float* Y;
    if (ws_size >= SPLIT_NEED) {
        k_attn<NSPLIT><<<NSPLIT * BB * 64, 256, 0, stream>>>(xf_t, G_bf, nullptr, O_part, mlbuf);
        Y = (float*)ws;                                // alias xf_bf+xf_t (dead after attn)
        k_combine<<<1920, 256, 0, stream>>>(O_part, mlbuf, Y);
    } else {
        Y = (float*)(ws + 6029312);
        k_attn<1><<<BB * 64, 256, 0, stream>>>(xf_t, G_bf, Y, nullptr, nullptr);
    }
    k_out<<<1920, 256, 0, stream>>>(Y, w_w, w_b, x, out);
}